// Round 5
// baseline (20910.567 us; speedup 1.0000x reference)
//
#include <hip/hip_runtime.h>
#include <math.h>

#define BATCH 16
#define TLEN 4096
#define KDIM 512
#define G3 1536

// recurrence partition: 8 groups (batch pairs) x 32 member blocks (16 units)
#define UBK 32           // unit-member blocks per group
#define GRP 8            // batch-pair groups
#define NBLK (UBK * GRP) // 256 persistent blocks (1 per CU)
#define UPB 16           // units per block
#define BPB 2            // batches per block
#define ROWS 48          // 3 gates * UPB
#define REC_THREADS 768  // 24 tiles (2 rows each) * 32 k-splits

#define HP 516           // h_s row pitch

#define H_OFF 0
#define GH_OFF (BPB * HP)              // 1032  [96]  (row*2+b)
#define XQ_OFF (GH_OFF + 96)           // 1128  [3][2][16]
#define BHN_OFF (XQ_OFF + 96)          // 1224  [16]  b_hh n-gate slice
#define SMEM_FLOATS (BHN_OFF + 16)     // 1240 used
#define SMEM_BYTES 86016               // padded to 84KB -> forces 1 block/CU

typedef __attribute__((ext_vector_type(4))) float f32x4;
typedef __attribute__((ext_vector_type(2))) unsigned u32x2;
typedef __attribute__((ext_vector_type(4))) unsigned u32x4;

__device__ __forceinline__ float fast_sigmoid(float x) {
  float e = __expf(-x);
  return __builtin_amdgcn_rcpf(1.f + e);
}
__device__ __forceinline__ float fast_tanh(float x) {
  float ax = fabsf(x);
  float e = __expf(-2.f * ax);
  float r = (1.f - e) * __builtin_amdgcn_rcpf(1.f + e);
  return copysignf(r, x);
}

// ---------------------------------------------------------------------------
// GEMM: xp_t = A[M,K] @ W[N,K]^T + b_ih (+ b_hh for gates r,z ONLY — the
// n-gate b_hn must stay inside r*(...) per GRU semantics). Output written in
// recurrence layout: xp_t[t][member(32)][group(8)][gate(3)][b&1][u&15]
// so each rec block reads one contiguous 384B slice per step.
// ---------------------------------------------------------------------------
__global__ __launch_bounds__(256)
void gemm_nt_bias(const float* __restrict__ A, const float* __restrict__ W,
                  const float* __restrict__ bias, const float* __restrict__ bias_hh,
                  float* __restrict__ C, int M, int N) {
  const int K = KDIM;
  __shared__ float As[16][132];
  __shared__ float Bs[16][132];
  int tid = threadIdx.x;
  int tx = tid & 15, ty = tid >> 4;
  int bx = blockIdx.x, by = blockIdx.y;
  const float* Ab = A + (size_t)by * 128 * K;
  const float* Wb = W + (size_t)bx * 128 * K;

  float acc[8][8];
#pragma unroll
  for (int i = 0; i < 8; i++)
#pragma unroll
    for (int j = 0; j < 8; j++) acc[i][j] = 0.f;

  for (int kk = 0; kk < K; kk += 16) {
    __syncthreads();
#pragma unroll
    for (int i = 0; i < 2; i++) {
      int task = tid + i * 256;
      int kc = task & 3;
      int mrow = task >> 2;
      float4 va = *(const float4*)(Ab + (size_t)mrow * K + kk + kc * 4);
      As[kc*4+0][mrow] = va.x; As[kc*4+1][mrow] = va.y;
      As[kc*4+2][mrow] = va.z; As[kc*4+3][mrow] = va.w;
      float4 vb = *(const float4*)(Wb + (size_t)mrow * K + kk + kc * 4);
      Bs[kc*4+0][mrow] = vb.x; Bs[kc*4+1][mrow] = vb.y;
      Bs[kc*4+2][mrow] = vb.z; Bs[kc*4+3][mrow] = vb.w;
    }
    __syncthreads();
#pragma unroll
    for (int k = 0; k < 16; k++) {
      float4 a0 = *(const float4*)&As[k][ty * 4];
      float4 a1 = *(const float4*)&As[k][64 + ty * 4];
      float4 b0 = *(const float4*)&Bs[k][tx * 4];
      float4 b1 = *(const float4*)&Bs[k][64 + tx * 4];
      float av[8] = {a0.x, a0.y, a0.z, a0.w, a1.x, a1.y, a1.z, a1.w};
      float bv[8] = {b0.x, b0.y, b0.z, b0.w, b1.x, b1.y, b1.z, b1.w};
#pragma unroll
      for (int i = 0; i < 8; i++)
#pragma unroll
        for (int j = 0; j < 8; j++) acc[i][j] += av[i] * bv[j];
    }
  }

#pragma unroll
  for (int hi = 0; hi < 2; hi++)
#pragma unroll
    for (int i = 0; i < 4; i++) {
      int mrow = by * 128 + hi * 64 + ty * 4 + i;
      int b = mrow >> 12;        // row / TLEN
      int t = mrow & (TLEN - 1);
#pragma unroll
      for (int hj = 0; hj < 2; hj++) {
        int n = bx * 128 + hj * 64 + tx * 4;
        int g = n >> 9;          // gate
        int unit = n & 511;
        float4 bb = *(const float4*)(bias + n);
        float4 b2 = {0.f, 0.f, 0.f, 0.f};
        if (n < 1024) b2 = *(const float4*)(bias_hh + n);   // r,z gates only
        float4 v;
        v.x = acc[hi*4+i][hj*4+0] + bb.x + b2.x;
        v.y = acc[hi*4+i][hj*4+1] + bb.y + b2.y;
        v.z = acc[hi*4+i][hj*4+2] + bb.z + b2.z;
        v.w = acc[hi*4+i][hj*4+3] + bb.w + b2.w;
        // xp_t[t][unit>>4][b>>1][g][b&1][unit&15]
        size_t dst = ((((size_t)t * UBK + (unit >> 4)) * GRP + (b >> 1)) * 3 + g)
                     * (BPB * UPB) + (size_t)(b & 1) * UPB + (unit & 15);
        *(float4*)(C + dst) = v;
      }
    }
}

// ---------------------------------------------------------------------------
// Persistent GRU recurrence. 256 blocks (8 batch-pair groups x 32 members),
// 768 threads, 84KB LDS (pad -> 1 block/CU, all 256 CUs busy).
//
// w_hh register-resident: thread (tile,ks) holds 2 rows x 16 k-floats.
// Per step: poll mailbox (value,tag) pairs -> LDS h stage -> barrier ->
// dot (h hoisted to 8 f32x4 regs, 64 FMA/thread) -> in-wave __shfl_xor
// butterfly over 32 k-split lanes -> gh_s -> barrier -> gates (32 thr) ->
// fused 8B (h_bits, tag) publish, fire-and-forget. Tags monotonic; parity-2
// buffering safe by step causality (see round-4 analysis).
// ---------------------------------------------------------------------------
__global__ __launch_bounds__(REC_THREADS, 1)
void gru_rec(const float* __restrict__ xp,     // transposed layout (see gemm)
             const float* __restrict__ w_hh,   // [1536,512]
             const float* __restrict__ b_hh,   // [1536]
             unsigned* __restrict__ mb,        // mailbox [2][GRP][1024] pairs
             unsigned flag_base,               // 0 layer1, TLEN layer2
             float* __restrict__ out,          // [B,T,512]
             int apply_gelu) {
  extern __shared__ float sm[];
  float* h_s   = sm + H_OFF;     // [2][HP]
  float* gh_s  = sm + GH_OFF;    // [96]  (row*2+b), row = gate*16+u
  float* xq_s  = sm + XQ_OFF;    // [3][2][16]
  float* bhn_s = sm + BHN_OFF;   // [16]  b_hh[1024 + u0 + u]

  const int tid = threadIdx.x;
  const int L = blockIdx.x;
  const int g = L & 7;           // group (batch pair)
  const int memb = L >> 3;       // member (unit block), 0..31
  const int u0 = memb * UPB;
  const int b0 = g * BPB;
  const float* xslice = xp + ((size_t)memb * GRP + g) * (3 * BPB * UPB);

  const int tile = tid >> 5;   // 0..23 (2-row tiles)
  const int ks = tid & 31;     // k-split lane

  // ---- w slice into registers: 2 rows x 4 f32x4 (k-interleaved) ----
  float4 wreg[2][4];
#pragma unroll
  for (int r = 0; r < 2; r++) {
    int row = tile * 2 + r;                  // 0..47 == gate*16 + u
    int gate = row >> 4, u = row & 15;
    const float* wrow = w_hh + (size_t)(gate * KDIM + u0 + u) * KDIM;
#pragma unroll
    for (int kk = 0; kk < 4; kk++)
      wreg[r][kk] = *(const float4*)(wrow + (size_t)(kk * 32 + ks) * 4);
  }
  if (tid < UPB) bhn_s[tid] = b_hh[2 * KDIM + u0 + tid];

  // prefetch x-slice for t=0 (one contiguous 384B chunk, 24 float4)
  float4 xq_reg = {0.f, 0.f, 0.f, 0.f};
  if (tid < 24) xq_reg = *(const float4*)(xslice + tid * 4);

  float hprev = 0.f;   // gate thread's own h(t-1)[b][u0+u]

  for (int t = 0; t < TLEN; t++) {
    // ---- stage h(t-1): poll mailbox pairs, payload rides with the tag ----
    if (t == 0) {
      for (int idx = tid; idx < BPB * KDIM; idx += REC_THREADS)
        h_s[(idx >> 9) * HP + (idx & 511)] = 0.f;
    } else {
      if (tid < 512) {
        const unsigned* src = mb + ((size_t)(((t + 1) & 1) * GRP + g) * 1024
                                    + (size_t)tid * 2) * 2;
        const unsigned tgt = flag_base + (unsigned)t;
        u32x4 pv;
        for (;;) {
          asm volatile("global_load_dwordx4 %0, %1, off sc0 sc1\n\ts_waitcnt vmcnt(0)"
                       : "=v"(pv) : "v"(src) : "memory");
          if (pv.y >= tgt && pv.w >= tgt) break;
        }
        int j0 = tid * 2;                       // pair index
        int mm = j0 >> 5, bb = (j0 >> 4) & 1, uu = j0 & 15;  // uu even
        float2 hv;
        hv.x = __uint_as_float(pv.x);
        hv.y = __uint_as_float(pv.z);
        *(float2*)(h_s + bb * HP + mm * 16 + uu) = hv;
      }
    }
    // publish this step's x-slice from the prefetch register
    if (tid < 24) *(float4*)(xq_s + tid * 4) = xq_reg;
    __syncthreads();

    // issue prefetch for t+1 (completes well before it's consumed next iter)
    if (tid < 24 && t + 1 < TLEN)
      xq_reg = *(const float4*)(xslice + (size_t)(t + 1) * (NBLK * 3 * BPB * UPB) + tid * 4);

    // ---- dot: 2 rows x 2 batches per thread; hoist all h loads first ----
    f32x4 hv0[4], hv1[4];
#pragma unroll
    for (int kk = 0; kk < 4; kk++) {
      int k4 = kk * 32 + ks;
      hv0[kk] = *(const f32x4*)(h_s + 0 * HP + k4 * 4);
      hv1[kk] = *(const f32x4*)(h_s + 1 * HP + k4 * 4);
    }
    float4 a00={0,0,0,0}, a01={0,0,0,0}, a10={0,0,0,0}, a11={0,0,0,0};
#pragma unroll
    for (int kk = 0; kk < 4; kk++) {
#define FMA4(d, wv, hv) d.x += wv.x*hv.x; d.y += wv.y*hv.y; d.z += wv.z*hv.z; d.w += wv.w*hv.w;
      FMA4(a00, wreg[0][kk], hv0[kk]) FMA4(a01, wreg[0][kk], hv1[kk])
      FMA4(a10, wreg[1][kk], hv0[kk]) FMA4(a11, wreg[1][kk], hv1[kk])
#undef FMA4
    }
    // ---- in-wave butterfly over the 32 k-split lanes (no LDS partials) ----
    float s0 = (a00.x + a00.y) + (a00.z + a00.w);   // r0 b0
    float s1 = (a01.x + a01.y) + (a01.z + a01.w);   // r0 b1
    float s2 = (a10.x + a10.y) + (a10.z + a10.w);   // r1 b0
    float s3 = (a11.x + a11.y) + (a11.z + a11.w);   // r1 b1
#pragma unroll
    for (int mk = 1; mk <= 16; mk <<= 1) {
      s0 += __shfl_xor(s0, mk, 64);
      s1 += __shfl_xor(s1, mk, 64);
      s2 += __shfl_xor(s2, mk, 64);
      s3 += __shfl_xor(s3, mk, 64);
    }
    if (ks < 4) {
      float v = (ks == 0) ? s0 : (ks == 1) ? s1 : (ks == 2) ? s2 : s3;
      gh_s[tile * 4 + ks] = v;     // index = (tile*2+r)*2 + b = row*2 + b
    }
    __syncthreads();

    // ---- gates + h update (32 threads: u = tid&15, b = tid>>4) ----
    if (tid < 32) {
      int u = tid & 15, b = tid >> 4;
      float xr = xq_s[0 * 32 + b * 16 + u];
      float xz = xq_s[1 * 32 + b * 16 + u];
      float xn = xq_s[2 * 32 + b * 16 + u];
      float ghr = gh_s[(0 * 16 + u) * 2 + b];
      float ghz = gh_s[(1 * 16 + u) * 2 + b];
      float ghn = gh_s[(2 * 16 + u) * 2 + b];
      float rg = fast_sigmoid(xr + ghr);          // b_ih+b_hh folded in GEMM
      float zg = fast_sigmoid(xz + ghz);
      float ng = fast_tanh(xn + rg * (ghn + bhn_s[u]));  // b_hn inside r*()
      float hn = (1.f - zg) * ng + zg * hprev;
      // fused payload+tag publish: single 8B store, fire-and-forget
      u32x2 pvs;
      pvs.x = __float_as_uint(hn);
      pvs.y = flag_base + (unsigned)t + 1u;
      unsigned* dst = mb + ((size_t)((t & 1) * GRP + g) * 1024
                            + (size_t)(memb * 32 + b * 16 + u)) * 2;
      asm volatile("global_store_dwordx2 %0, %1, off sc0 sc1"
                   :: "v"(dst), "v"(pvs) : "memory");
      hprev = hn;
      // off-critical-path epilogue: GELU + out store
      float ov = hn;
      if (apply_gelu) ov = 0.5f * hn * (1.f + erff(hn * 0.70710678118654752f));
      out[((size_t)((b0 + b) * TLEN + t)) * KDIM + u0 + u] = ov;
    }
  }
}

// ---------------------------------------------------------------------------
// ws layout: [0, 402.65MB) xp_t | mailbox 128KB
// ---------------------------------------------------------------------------
extern "C" void kernel_launch(void* const* d_in, const int* in_sizes, int n_in,
                              void* d_out, int out_size, void* d_ws, size_t ws_size,
                              hipStream_t stream) {
  const float* x     = (const float*)d_in[0];
  const float* w_ih1 = (const float*)d_in[1];
  const float* w_hh1 = (const float*)d_in[2];
  const float* b_ih1 = (const float*)d_in[3];
  const float* b_hh1 = (const float*)d_in[4];
  const float* w_ih2 = (const float*)d_in[5];
  const float* w_hh2 = (const float*)d_in[6];
  const float* b_ih2 = (const float*)d_in[7];
  const float* b_hh2 = (const float*)d_in[8];
  float* y = (float*)d_out;

  char* ws = (char*)d_ws;
  const size_t XPB = (size_t)BATCH * TLEN * G3 * sizeof(float);
  float*    xp = (float*)ws;
  unsigned* mb = (unsigned*)(ws + XPB);

  hipFuncSetAttribute((const void*)gru_rec,
                      hipFuncAttributeMaxDynamicSharedMemorySize, SMEM_BYTES);
  // mailbox: 2 parities x 8 groups x 1024 pairs x 8B = 128 KiB
  hipMemsetAsync(mb, 0, (size_t)2 * GRP * 1024 * 2 * sizeof(unsigned), stream);

  dim3 gg(12, 512), tb(256);
  const int M = BATCH * TLEN;

  gemm_nt_bias<<<gg, tb, 0, stream>>>(x, w_ih1, b_ih1, b_hh1, xp, M, G3);
  gru_rec<<<dim3(NBLK), REC_THREADS, SMEM_BYTES, stream>>>(xp, w_hh1, b_hh1, mb, 0u, y, 1);
  gemm_nt_bias<<<gg, tb, 0, stream>>>(y, w_ih2, b_ih2, b_hh2, xp, M, G3);
  gru_rec<<<dim3(NBLK), REC_THREADS, SMEM_BYTES, stream>>>(xp, w_hh2, b_hh2, mb, (unsigned)TLEN, y, 0);
}